// Round 15
// baseline (238.946 us; speedup 1.0000x reference)
//
#include <hip/hip_runtime.h>

// Problem constants (fixed by setup_inputs)
constexpr int Bn = 128, Cn = 3, Sn = 256;
constexpr int HWn = Sn * Sn;          // 65536
constexpr int NPLANE = Bn * Cn;       // 384
constexpr float DTf = 0.05f;
constexpr float EPSf = 1e-6f;
constexpr float MAXCf = 1.0f;

// ws float layout:
//   [128..10111]    tapx [3 c][13 d][256 i]   (zero for OOB sources)
//   [10368..20351]  tapy [3 c][13 d][256 i]   (dg^3 folded in; zero for OOB)
#define WS_TAPX 128
#define WS_TAPY 10368

// ---- build composed banded operator taps (+ fused spatial mean) ----------
// All T_k = I + r_k*L commute; composed X (resp Y) = product of the three
// x-dir (y-dir) tridiagonal inverses. Thread j applies the three EXACT
// reference Thomas solves (incl. b0+eps, denom clamp, x_n = dp_n) to basis
// vector e_j, keeping rows [j-16, j+16] in registers. Band +-6 tail ~3e-10.
__global__ void build_taps(const float* __restrict__ alpha_base,
                           const float* __restrict__ beta_base,
                           const float* __restrict__ aspat,
                           const float* __restrict__ bspat,
                           const float* __restrict__ coupling,
                           float* __restrict__ ws) {
  __shared__ double sm[256];
  __shared__ float cp3[3][288], di3[3][288];   // padded: idx = i+16, zeros outside [0,255]
  __shared__ float s_mean;
  const int dirc = blockIdx.x, dir = dirc / 3, c = dirc % 3;
  const int j = threadIdx.x;
  {
    const float4* p = (const float4*)((dir == 0 ? aspat : bspat) + c * HWn) + j;
    double acc = 0.0;
#pragma unroll
    for (int k2 = 0; k2 < 64; ++k2) {
      float4 v = p[k2 * 256];
      acc += (double)v.x + (double)v.y + (double)v.z + (double)v.w;
    }
    sm[j] = acc;
    __syncthreads();
    for (int s2 = 128; s2 > 0; s2 >>= 1) {
      if (j < s2) sm[j] += sm[j + s2];
      __syncthreads();
    }
    if (j == 0) s_mean = (float)(sm[0] * (1.0 / 65536.0));
    __syncthreads();
  }
  if (j < 3) {
    const int k = j;
    const float base = (dir == 0) ? alpha_base[c] : beta_base[c];
    const float coef = fminf(fmaxf(base + s_mean * ((float)k * DTf), EPSf), MAXCf);
    const float r = coef * (DTf * 0.5f);       // DX = 1
    for (int p = 0; p < 16; ++p) {
      cp3[k][p] = 0.f; di3[k][p] = 0.f;
      cp3[k][272 + p] = 0.f; di3[k][272 + p] = 0.f;
    }
    float b0 = 1.f + r + EPSf;                 // reference: b[0] + eps
    float cq = -r / b0, dq = 1.f / b0;
    cp3[k][16] = cq; di3[k][16] = dq;
    for (int i = 1; i < 256; ++i) {
      float b = (i == 255) ? (1.f + r) : (1.f + 2.f * r);
      float den = fmaxf(b + r * cq, EPSf);     // b - a*cp_prev, a = -r
      cq = -r / den; dq = 1.f / den;
      cp3[k][16 + i] = cq; di3[k][16 + i] = dq;
    }
  }
  float* tb = ws + ((dir == 0) ? WS_TAPX : WS_TAPY) + c * 13 * 256;
#pragma unroll
  for (int d = 0; d < 13; ++d) tb[d * 256 + j] = 0.f;   // OOB-source taps stay 0
  __syncthreads();

  float z[33];                                  // o = 0..32 <-> row i = j-16+o
#pragma unroll
  for (int o = 0; o < 33; ++o) z[o] = (o == 16) ? 1.f : 0.f;
#pragma unroll
  for (int k = 0; k < 3; ++k) {
    float dp = 0.f;
#pragma unroll
    for (int o = 0; o < 33; ++o) {              // forward: dp in place
      const int p = j + o;
      dp = fmaf(-cp3[k][p], dp, z[o] * di3[k][p]);
      z[o] = dp;
    }
    float x = 0.f;
#pragma unroll
    for (int o = 32; o >= 0; --o) {             // backward: x = dp - cp*x_next
      const int p = j + o;
      x = fmaf(-cp3[k][p], x, z[o]);
      z[o] = x;
    }
  }
  float scale = 1.f;
  if (dir == 1) {
    float dgc = coupling[c * 3 + c];
    scale = dgc * dgc * dgc;                    // diag applied after each step
  }
#pragma unroll
  for (int o = -6; o <= 6; ++o) {
    const int i = j + o;                        // output row; d = 6 - o
    if ((unsigned)i < 256u) tb[(6 - o) * 256 + i] = z[o + 16] * scale;
  }
}

// ---- hot kernel: out = Y * u * X^T as a PIPELINED separable stencil -------
// Block = (plane, 64-row stripe R). Window rows r in [0,76) <-> global rows
// 64R-6+r (clamped; zero taps kill garbage). 11 iterations:
//   phase A: DMA-stage 8 u-rows (1 global_load_lds per wave, 1KB dense)
//            || y-conv batch j=i-3: 2 rows/thread from cyclic V buffer,
//               per-row taps via wave-uniform s_load, dense float2 stores
//   barrier
//   phase B: x-conv 8 rows: 4-col segs, Ubuf->Vbuf, interior taps uniform,
//            cols 0-5/250-255 fixed with per-col taps (zero-padded)
//   barrier
// Cyclic Vbuf = 32 rows (lag-3 schedule: x(i) writes slots (8i..8i+7)&31;
// y(j=i-3) reads rows 8j..8j+19 = 8i-24..8i-5 — disjoint mod 32, and its
// last use of any row precedes that slot's overwrite by one full iteration).
// LDS 42.5 KB -> 3 blocks/CU; (512,6) caps VGPR at 85 -> 24 waves/CU.
// Strides 266 (mod 32 = 10) spread x's strided LDS accesses <=2-way.
__global__ __launch_bounds__(512, 6) void conv_pipe(
    const float* __restrict__ src, float* __restrict__ dst,
    const float* __restrict__ ws) {
  __shared__ float Vb[32 * 266];               // 34048 B
  __shared__ float Ub[8 * 266];                // 8512 B
  const int t = threadIdx.x;
  // XCD-bijective swizzle: 1536 = 8*192 (plane stripes grouped per XCD)
  const int logical = (blockIdx.x & 7) * 192 + (blockIdx.x >> 3);
  const int plane = logical >> 2;
  const int R = logical & 3;
  const int c = plane % 3;
  const float* tpx = ws + WS_TAPX + c * 3328;
  const float* tpy = ws + WS_TAPY + c * 3328;
  const float* srcp = src + (size_t)plane * HWn;
  float* dstp = dst + (size_t)plane * HWn;
  const int g_base = 64 * R - 6;               // window r=0 <-> global g_base+r

  float tx[13];                                 // interior x-taps (uniform)
#pragma unroll
  for (int d = 0; d < 13; ++d) tx[d] = tpx[d * 256 + 128];

  const int xs = t >> 3, xr = t & 7;           // x: 64 segs(4col) x 8 rows
  const int yp = t & 127, ysub = t >> 7;       // y: 128 col-pairs x 4 subs
  const int wv = t >> 6, l = t & 63;           // stage: wave -> Ubuf row

  for (int i = 0; i < 11; ++i) {
    // ---------------- phase A: stage(i) || y(i-3) ----------------
    if (i < 10) {
      const int r = 8 * i + wv;
      if (r < 76) {
        int G = g_base + r;
        G = G < 0 ? 0 : (G > 255 ? 255 : G);
        const float* gp = srcp + (size_t)G * 256 + 4 * l;
        __builtin_amdgcn_global_load_lds(
            (const __attribute__((address_space(1))) void*)gp,
            (__attribute__((address_space(3))) void*)(Ub + wv * 266), 16, 0, 0);
      }
    }
    if (i >= 3) {
      const int j = i - 3;
      const int r0 = 6 + 8 * j + 2 * ysub;     // out window rows r0, r0+1
      const int g0 = g_base + r0;              // in [64R, 64R+63) always valid
      float2 win[14];                          // V rows r0-6 .. r0+7, one pair
#pragma unroll
      for (int d = 0; d < 14; ++d) {
        const int slot = (r0 - 6 + d) & 31;
        win[d] = *(const float2*)(Vb + slot * 266 + 2 * yp);
      }
      const int gu = __builtin_amdgcn_readfirstlane(g0);
      float ox0, oy0, ox1, oy1;
      {
        const float ty0 = tpy[gu];             // d = 0
        ox0 = ty0 * win[0].x; oy0 = ty0 * win[0].y;
        const float ty1 = tpy[gu + 1];
        ox1 = ty1 * win[1].x; oy1 = ty1 * win[1].y;
      }
#pragma unroll
      for (int d = 1; d < 13; ++d) {
        const float ty0 = tpy[d * 256 + gu];   // wave-uniform -> s_load
        ox0 = fmaf(ty0, win[d].x, ox0); oy0 = fmaf(ty0, win[d].y, oy0);
        const float ty1 = tpy[d * 256 + gu + 1];
        ox1 = fmaf(ty1, win[d + 1].x, ox1); oy1 = fmaf(ty1, win[d + 1].y, oy1);
      }
      *(float2*)(dstp + (size_t)g0 * 256 + 2 * yp) = make_float2(ox0, oy0);
      *(float2*)(dstp + (size_t)(g0 + 1) * 256 + 2 * yp) = make_float2(ox1, oy1);
    }
    asm volatile("s_waitcnt vmcnt(0)" ::: "memory");   // own DMA done
    __syncthreads();
    // ---------------- phase B: x(i) ----------------
    if (i < 10) {
      const int r = 8 * i + xr;
      if (r < 76) {
        float in_[16];                         // cols [4xs-6, 4xs+10)
#pragma unroll
        for (int m = 0; m < 8; ++m) {
          int cp = 4 * xs - 6 + 2 * m;
          cp = cp < 0 ? 0 : (cp > 254 ? 254 : cp);
          *(float2*)&in_[2 * m] = *(const float2*)(Ub + xr * 266 + cp);
        }
        float acc[4];
#pragma unroll
        for (int e = 0; e < 4; ++e) acc[e] = tx[0] * in_[e];
#pragma unroll
        for (int d = 1; d < 13; ++d)
#pragma unroll
          for (int e = 0; e < 4; ++e) acc[e] = fmaf(tx[d], in_[e + d], acc[e]);
        if (xs < 2) {                          // true taps for cols 0..5
#pragma unroll
          for (int e = 0; e < 4; ++e) {
            const int col = 4 * xs + e;
            if (col < 6) {
              float a = 0.f;
#pragma unroll
              for (int d = 0; d < 13; ++d)
                a = fmaf(tpx[d * 256 + col], in_[e + d], a);
              acc[e] = a;
            }
          }
        } else if (xs >= 62) {                 // true taps for cols 250..255
#pragma unroll
          for (int e = 0; e < 4; ++e) {
            const int col = 4 * xs + e;
            if (col >= 250) {
              float a = 0.f;
#pragma unroll
              for (int d = 0; d < 13; ++d)
                a = fmaf(tpx[d * 256 + col], in_[e + d], a);
              acc[e] = a;
            }
          }
        }
        const int slot = r & 31;
        *(float4*)(Vb + slot * 266 + 4 * xs) =
            make_float4(acc[0], acc[1], acc[2], acc[3]);
      }
    }
    __syncthreads();
  }
}

extern "C" void kernel_launch(void* const* d_in, const int* in_sizes, int n_in,
                              void* d_out, int out_size, void* d_ws, size_t ws_size,
                              hipStream_t stream) {
  const float* u = (const float*)d_in[0];
  const float* alpha_base = (const float*)d_in[1];
  const float* beta_base = (const float*)d_in[2];
  const float* alpha_spatial = (const float*)d_in[3];
  const float* beta_spatial = (const float*)d_in[4];
  const float* coupling = (const float*)d_in[5];
  float* out = (float*)d_out;
  float* ws = (float*)d_ws;

  build_taps<<<6, 256, 0, stream>>>(alpha_base, beta_base,
                                    alpha_spatial, beta_spatial, coupling, ws);
  conv_pipe<<<NPLANE * 4, 512, 0, stream>>>(u, out, ws);
}

// Round 16
// 170.934 us; speedup vs baseline: 1.3979x; 1.3979x over previous
//
#include <hip/hip_runtime.h>

// Problem constants (fixed by setup_inputs)
constexpr int Bn = 128, Cn = 3, Sn = 256;
constexpr int HWn = Sn * Sn;          // 65536
constexpr int NPLANE = Bn * Cn;       // 384
constexpr float DTf = 0.05f;
constexpr float EPSf = 1e-6f;
constexpr float MAXCf = 1.0f;

// ws float layout:
//   [128..10111]    tapx [3 c][13 d][256 i]   (zero for OOB sources)
//   [10368..20351]  tapy [3 c][13 d][256 i]   (dg^3 folded in; zero for OOB)
//   [20480..]       tmp  [384][256][256]  (x-convolved field), if ws permits
#define WS_TAPX 128
#define WS_TAPY 10368
#define WS_TMP  20480

// ---- build composed banded operator taps (+ fused spatial mean) ----------
__global__ void build_taps(const float* __restrict__ alpha_base,
                           const float* __restrict__ beta_base,
                           const float* __restrict__ aspat,
                           const float* __restrict__ bspat,
                           const float* __restrict__ coupling,
                           float* __restrict__ ws) {
  __shared__ double sm[256];
  __shared__ float cp3[3][288], di3[3][288];   // padded: idx = i+16, zeros outside [0,255]
  __shared__ float s_mean;
  const int dirc = blockIdx.x, dir = dirc / 3, c = dirc % 3;
  const int j = threadIdx.x;
  {
    const float4* p = (const float4*)((dir == 0 ? aspat : bspat) + c * HWn) + j;
    double acc = 0.0;
#pragma unroll
    for (int k2 = 0; k2 < 64; ++k2) {
      float4 v = p[k2 * 256];
      acc += (double)v.x + (double)v.y + (double)v.z + (double)v.w;
    }
    sm[j] = acc;
    __syncthreads();
    for (int s2 = 128; s2 > 0; s2 >>= 1) {
      if (j < s2) sm[j] += sm[j + s2];
      __syncthreads();
    }
    if (j == 0) s_mean = (float)(sm[0] * (1.0 / 65536.0));
    __syncthreads();
  }
  if (j < 3) {
    const int k = j;
    const float base = (dir == 0) ? alpha_base[c] : beta_base[c];
    const float coef = fminf(fmaxf(base + s_mean * ((float)k * DTf), EPSf), MAXCf);
    const float r = coef * (DTf * 0.5f);       // DX = 1
    for (int p = 0; p < 16; ++p) {
      cp3[k][p] = 0.f; di3[k][p] = 0.f;
      cp3[k][272 + p] = 0.f; di3[k][272 + p] = 0.f;
    }
    float b0 = 1.f + r + EPSf;                 // reference: b[0] + eps
    float cq = -r / b0, dq = 1.f / b0;
    cp3[k][16] = cq; di3[k][16] = dq;
    for (int i = 1; i < 256; ++i) {
      float b = (i == 255) ? (1.f + r) : (1.f + 2.f * r);
      float den = fmaxf(b + r * cq, EPSf);     // b - a*cp_prev, a = -r
      cq = -r / den; dq = 1.f / den;
      cp3[k][16 + i] = cq; di3[k][16 + i] = dq;
    }
  }
  float* tb = ws + ((dir == 0) ? WS_TAPX : WS_TAPY) + c * 13 * 256;
#pragma unroll
  for (int d = 0; d < 13; ++d) tb[d * 256 + j] = 0.f;   // OOB-source taps stay 0
  __syncthreads();

  float z[33];                                  // o = 0..32 <-> row i = j-16+o
#pragma unroll
  for (int o = 0; o < 33; ++o) z[o] = (o == 16) ? 1.f : 0.f;
#pragma unroll
  for (int k = 0; k < 3; ++k) {
    float dp = 0.f;
#pragma unroll
    for (int o = 0; o < 33; ++o) {              // forward: dp in place
      const int p = j + o;
      dp = fmaf(-cp3[k][p], dp, z[o] * di3[k][p]);
      z[o] = dp;
    }
    float x = 0.f;
#pragma unroll
    for (int o = 32; o >= 0; --o) {             // backward: x = dp - cp*x_next
      const int p = j + o;
      x = fmaf(-cp3[k][p], x, z[o]);
      z[o] = x;
    }
  }
  float scale = 1.f;
  if (dir == 1) {
    float dgc = coupling[c * 3 + c];
    scale = dgc * dgc * dgc;                    // diag applied after each step
  }
#pragma unroll
  for (int o = -6; o <= 6; ++o) {
    const int i = j + o;                        // output row; d = 6 - o
    if ((unsigned)i < 256u) tb[(6 - o) * 256 + i] = z[o + 16] * scale;
  }
}

// ---- streaming kernel 1: tmp = u * X^T (x-conv along rows) ---------------
// No LDS, no barriers. Thread = (row, 16-col seg): 8 clamped float4 loads,
// interior taps via block-uniform s_load; cols 0-5/250-255 recomputed with
// true per-col taps (zero taps kill clamped-garbage inputs). Dense stores.
__global__ __launch_bounds__(256, 4) void convx(
    const float* __restrict__ src, float* __restrict__ tmp,
    const float* __restrict__ ws) {
  const int t = threadIdx.x;
  const int rid = blockIdx.x * 16 + (t >> 4);  // global row id (plane-uniform/blk)
  const int s = t & 15;
  const int c = (rid >> 8) % 3;
  const float* tpx = ws + WS_TAPX + c * 3328;
  float tx[13];
#pragma unroll
  for (int d = 0; d < 13; ++d) tx[d] = tpx[d * 256 + 128];  // uniform -> s_load
  const float* row = src + (size_t)rid * 256;
  float in_[32];                               // cols [16s-8, 16s+24), clamped
#pragma unroll
  for (int mq = 0; mq < 8; ++mq) {
    int cl = 16 * s - 8 + 4 * mq;
    cl = cl < 0 ? 0 : (cl > 252 ? 252 : cl);
    *(float4*)&in_[4 * mq] = *(const float4*)(row + cl);
  }
  float acc[16];
#pragma unroll
  for (int e = 0; e < 16; ++e) acc[e] = tx[0] * in_[e + 2];
#pragma unroll
  for (int d = 1; d < 13; ++d)
#pragma unroll
    for (int e = 0; e < 16; ++e) acc[e] = fmaf(tx[d], in_[e + 2 + d], acc[e]);
  if (s == 0) {                                // fix cols 0..5 (true taps)
#pragma unroll
    for (int e = 0; e < 6; ++e) {
      float ac = 0.f;
#pragma unroll
      for (int d = 0; d < 13; ++d) ac = fmaf(tpx[d * 256 + e], in_[e + 2 + d], ac);
      acc[e] = ac;
    }
  } else if (s == 15) {                        // fix cols 250..255
#pragma unroll
    for (int e = 10; e < 16; ++e) {
      float ac = 0.f;
#pragma unroll
      for (int d = 0; d < 13; ++d) ac = fmaf(tpx[d * 256 + 240 + e], in_[e + 2 + d], ac);
      acc[e] = ac;
    }
  }
  float* op = tmp + (size_t)rid * 256 + 16 * s;
#pragma unroll
  for (int jj = 0; jj < 4; ++jj)
    *(float4*)(op + 4 * jj) =
        make_float4(acc[4 * jj], acc[4 * jj + 1], acc[4 * jj + 2], acc[4 * jj + 3]);
}

// ---- streaming kernel 2: out = Y * tmp (y-conv along columns) ------------
// No LDS, no barriers. Thread = (col-pair, 32-row chunk): rolling float2
// win[13]; row taps wave-uniform s_load; clamped row reads pair with zero
// taps. tmp is L3-resident (written by convx just before). Dense stores.
__global__ __launch_bounds__(256, 4) void convy(
    const float* __restrict__ tmp, float* __restrict__ dst,
    const float* __restrict__ ws) {
  const int t = threadIdx.x;
  const int plane = blockIdx.x >> 2;
  const int chunk = (blockIdx.x & 3) * 2 + (t >> 7);   // 0..7, wave-uniform
  const int pair = t & 127;
  const int c = plane % 3;
  const float* tpy = ws + WS_TAPY + c * 3328;
  const float* tp = tmp + (size_t)plane * HWn + 2 * pair;
  float* dp = dst + (size_t)plane * HWn + 2 * pair;
  const int g0 = 32 * chunk;
  float2 win[13];                              // rows g-6 .. g+6 of this pair
#pragma unroll
  for (int m = 0; m < 12; ++m) {
    int gg = g0 - 6 + m;
    gg = gg < 0 ? 0 : gg;                      // clamped read x zero tap
    win[m] = *(const float2*)(tp + (size_t)gg * 256);
  }
#pragma unroll
  for (int rr = 0; rr < 32; ++rr) {
    const int g = g0 + rr;
    {
      int gg = g + 6;
      gg = gg > 255 ? 255 : gg;
      win[12] = *(const float2*)(tp + (size_t)gg * 256);
    }
    const int gu = __builtin_amdgcn_readfirstlane(g);
    float ox, oy;
    {
      const float ty = tpy[gu];                // wave-uniform -> s_load
      ox = ty * win[0].x; oy = ty * win[0].y;
    }
#pragma unroll
    for (int d = 1; d < 13; ++d) {
      const float ty = tpy[d * 256 + gu];
      ox = fmaf(ty, win[d].x, ox);
      oy = fmaf(ty, win[d].y, oy);
    }
    *(float2*)(dp + (size_t)g * 256) = make_float2(ox, oy);
#pragma unroll
    for (int m = 0; m < 12; ++m) win[m] = win[m + 1];
  }
}

// ---- fallback (R13-proven fused kernel, used only if ws lacks tmp room) ---
__global__ __launch_bounds__(512, 4) void conv3(
    const float* __restrict__ src, float* __restrict__ dst,
    const float* __restrict__ ws) {
  __shared__ float vt[76 * 256];               // 77824 B
  const int t = threadIdx.x;
  const int logical = (blockIdx.x & 7) * 192 + (blockIdx.x >> 3);
  const int plane = logical >> 2;
  const int st = logical & 3;
  const int c = plane % 3;
  const int h0 = st * 64;
  const int a = (st == 0) ? 0 : (h0 - 6);
  const int b = (st == 3) ? 256 : (h0 + 70);
  const int Wv = b - a;
  const float* tpx = ws + WS_TAPX + c * 3328;
  const float* tpy = ws + WS_TAPY + c * 3328;
  float tx[13];
#pragma unroll
  for (int d = 0; d < 13; ++d) tx[d] = tpx[d * 256 + 128];
  const float* srcp = src + (size_t)plane * HWn;

  const int NU = 16 * Wv;
#pragma unroll
  for (int p = 0; p < 3; ++p) {
    const int u = t + 512 * p;
    if (u < NU) {
      const int s = u & 15, rl = u >> 4;
      const float* row = srcp + (size_t)(a + rl) * 256;
      float in_[32];
#pragma unroll
      for (int mq = 0; mq < 8; ++mq) {
        int cl = 16 * s - 8 + 4 * mq;
        cl = cl < 0 ? 0 : (cl > 252 ? 252 : cl);
        *(float4*)&in_[4 * mq] = *(const float4*)(row + cl);
      }
      float acc[16];
#pragma unroll
      for (int e = 0; e < 16; ++e) acc[e] = tx[0] * in_[e + 2];
#pragma unroll
      for (int d = 1; d < 13; ++d)
#pragma unroll
        for (int e = 0; e < 16; ++e) acc[e] = fmaf(tx[d], in_[e + 2 + d], acc[e]);
      if (s == 0) {
#pragma unroll
        for (int e = 0; e < 6; ++e) {
          float ac = 0.f;
#pragma unroll
          for (int d = 0; d < 13; ++d) ac = fmaf(tpx[d * 256 + e], in_[e + 2 + d], ac);
          acc[e] = ac;
        }
      } else if (s == 15) {
#pragma unroll
        for (int e = 10; e < 16; ++e) {
          float ac = 0.f;
#pragma unroll
          for (int d = 0; d < 13; ++d) ac = fmaf(tpx[d * 256 + 240 + e], in_[e + 2 + d], ac);
          acc[e] = ac;
        }
      }
      const int sw = rl & 7;
      float4* vr = (float4*)vt + rl * 64;
#pragma unroll
      for (int jj = 0; jj < 4; ++jj)
        vr[(4 * s + jj) ^ sw] =
            make_float4(acc[4 * jj], acc[4 * jj + 1], acc[4 * jj + 2], acc[4 * jj + 3]);
    }
  }
  __syncthreads();

  const int pr = t & 127, rc = t >> 7;
  const int jq = pr >> 1, jin = (pr & 1) * 2;
  const int g0 = h0 + 16 * rc;
  float2 win[13];
#pragma unroll
  for (int m = 0; m < 12; ++m) {
    int gg = g0 - 6 + m;
    gg = gg < a ? a : gg;
    const int rl = gg - a;
    win[m] = *(const float2*)(vt + rl * 256 + (((jq ^ (rl & 7)) << 2) | jin));
  }
  float* dstp = dst + (size_t)plane * HWn + 2 * pr;
#pragma unroll
  for (int rr = 0; rr < 16; ++rr) {
    const int g = g0 + rr;
    {
      int gg = g + 6;
      gg = gg > b - 1 ? b - 1 : gg;
      const int rl = gg - a;
      win[12] = *(const float2*)(vt + rl * 256 + (((jq ^ (rl & 7)) << 2) | jin));
    }
    const int gu = __builtin_amdgcn_readfirstlane(g);
    float ox, oy;
    {
      const float ty = tpy[gu];
      ox = ty * win[0].x; oy = ty * win[0].y;
    }
#pragma unroll
    for (int d = 1; d < 13; ++d) {
      const float ty = tpy[d * 256 + gu];
      ox = fmaf(ty, win[d].x, ox);
      oy = fmaf(ty, win[d].y, oy);
    }
    *(float2*)(dstp + (size_t)g * 256) = make_float2(ox, oy);
#pragma unroll
    for (int m = 0; m < 12; ++m) win[m] = win[m + 1];
  }
}

extern "C" void kernel_launch(void* const* d_in, const int* in_sizes, int n_in,
                              void* d_out, int out_size, void* d_ws, size_t ws_size,
                              hipStream_t stream) {
  const float* u = (const float*)d_in[0];
  const float* alpha_base = (const float*)d_in[1];
  const float* beta_base = (const float*)d_in[2];
  const float* alpha_spatial = (const float*)d_in[3];
  const float* beta_spatial = (const float*)d_in[4];
  const float* coupling = (const float*)d_in[5];
  float* out = (float*)d_out;
  float* ws = (float*)d_ws;

  build_taps<<<6, 256, 0, stream>>>(alpha_base, beta_base,
                                    alpha_spatial, beta_spatial, coupling, ws);
  const size_t need = (size_t)(WS_TMP + (size_t)NPLANE * HWn) * sizeof(float);
  if (ws_size >= need) {
    float* tmp = ws + WS_TMP;
    convx<<<NPLANE * 16, 256, 0, stream>>>(u, tmp, ws);
    convy<<<NPLANE * 4, 256, 0, stream>>>(tmp, out, ws);
  } else {
    conv3<<<NPLANE * 4, 512, 0, stream>>>(u, out, ws);
  }
}